// Round 3
// 159.299 us; speedup vs baseline: 1.0704x; 1.0704x over previous
//
#include <hip/hip_runtime.h>
#include <math.h>

// Problem constants (fixed by setup_inputs)
#define W_ 192
#define H_ 192
#define D_ 160
#define B_ 2
#define HW_ (H_ * W_)

#define TX 32             // output tile x
#define TY 16             // output tile y
#define HY 20             // halo rows (TY + 4)
#define RAWP 41           // raw row stride, 40 data cols + odd stride (<=2-way banks)
#define RSP  33           // rowsum row stride, 32 data cols + odd stride (<=2-way banks)
#define CHUNK 20          // z-planes of output per block
#define PLANES (CHUNK + 4)
#define GX 6              // 192/32
#define GY 12             // 192/16
#define GZ 16             // 8 z-chunks * 2 batches
#define NBLK (GX * GY * GZ)   // 1152
#define NTOT 11796480.0f      // 2*1*160*192*192

__global__ __launch_bounds__(256) void lncc_main(const float* __restrict__ src,
                                                 const float* __restrict__ tgt,
                                                 float* __restrict__ partial) {
    // SoA float LDS, double-buffered for the 1-barrier/plane pipeline.
    __shared__ float rawS[2][HY][RAWP];
    __shared__ float rawT[2][HY][RAWP];
    __shared__ float rsS [2][HY][RSP];
    __shared__ float rsT [2][HY][RSP];
    __shared__ float rsS2[2][HY][RSP];
    __shared__ float rsT2[2][HY][RSP];
    __shared__ float rsST[2][HY][RSP];
    __shared__ float wsum[4];

    const int tid = threadIdx.x;
    const int bz  = blockIdx.z;
    const int b   = bz >> 3;                 // 8 chunks per batch
    const int z0  = (bz & 7) * CHUNK;
    const int bx0 = blockIdx.x * TX - 4;     // raw col 0 <-> gx = bx0 (16B-aligned)
    const int by0 = blockIdx.y * TY - 2;

    // ---- staging decode: tid<200 loads one aligned float4 per array ----
    const int  sr  = tid / 10;               // row 0..19
    const int  sc4 = tid - sr * 10;          // float4 col 0..9
    const int  sc  = sc4 * 4;                // word col 0,4,..,36
    const int  sgx = bx0 + sc;               // multiple of 4 -> float4 aligned
    const int  sgy = by0 + sr;
    const bool sW  = (tid < 200);
    const bool sOk = sW && ((unsigned)sgx < (unsigned)W_) && ((unsigned)sgy < (unsigned)H_);
    const size_t sOff = (size_t)sgy * W_ + (size_t)sgx;   // valid only when sOk

    // ---- phase1 decode: 16 x-pairs x 20 rows in two reps ----
    const int  p0y = tid >> 4;               // rows 0..15 (all threads)
    const int  p1y = p0y + 16;               // rows 16..19 (tid<64)
    const int  xp  = tid & 15;
    const bool p1  = (tid < 64);
    const int  rc  = 2 * xp + 2;             // raw read col base (window of out 2*xp)
    const int  wc  = 2 * xp;                 // rs write col base

    // ---- phase2 decode: thread owns output rows (y0, y0+1) at column tx ----
    const int tx = tid & 31;                 // 0..31
    const int y0 = (tid >> 5) * 2;           // 0,2,..,14

    // z-ring as float2 (x = row y0, y = row y0+1). Static member access only.
    float2 q0s=make_float2(0,0),q0t=make_float2(0,0),q0a=make_float2(0,0),q0b=make_float2(0,0),q0c=make_float2(0,0);
    float2 q1s=make_float2(0,0),q1t=make_float2(0,0),q1a=make_float2(0,0),q1b=make_float2(0,0),q1c=make_float2(0,0);
    float2 q2s=make_float2(0,0),q2t=make_float2(0,0),q2a=make_float2(0,0),q2b=make_float2(0,0),q2c=make_float2(0,0);
    float2 q3s=make_float2(0,0),q3t=make_float2(0,0),q3a=make_float2(0,0),q3b=make_float2(0,0),q3c=make_float2(0,0);
    float2 q4s=make_float2(0,0),q4t=make_float2(0,0),q4a=make_float2(0,0),q4b=make_float2(0,0),q4c=make_float2(0,0);
    float2 zS=make_float2(0,0),zT=make_float2(0,0),zA=make_float2(0,0),zB=make_float2(0,0),zC=make_float2(0,0);
    float lsum = 0.0f;

    // phase2: y-sums of rowsums for plane j (buffer rbuf) + z-window + LNCC
    auto phase2 = [&](int rbuf, int j) {
        float2 yS, yT, yA, yB, yC;
        {
            const float* p = &rsS[rbuf][y0][tx];
            float l0=p[0], l1=p[RSP], l2=p[2*RSP], l3=p[3*RSP], l4=p[4*RSP], l5=p[5*RSP];
            float m = l1 + l2 + l3 + l4;
            yS.x = l0 + m;  yS.y = m + l5;
        }
        {
            const float* p = &rsT[rbuf][y0][tx];
            float l0=p[0], l1=p[RSP], l2=p[2*RSP], l3=p[3*RSP], l4=p[4*RSP], l5=p[5*RSP];
            float m = l1 + l2 + l3 + l4;
            yT.x = l0 + m;  yT.y = m + l5;
        }
        {
            const float* p = &rsS2[rbuf][y0][tx];
            float l0=p[0], l1=p[RSP], l2=p[2*RSP], l3=p[3*RSP], l4=p[4*RSP], l5=p[5*RSP];
            float m = l1 + l2 + l3 + l4;
            yA.x = l0 + m;  yA.y = m + l5;
        }
        {
            const float* p = &rsT2[rbuf][y0][tx];
            float l0=p[0], l1=p[RSP], l2=p[2*RSP], l3=p[3*RSP], l4=p[4*RSP], l5=p[5*RSP];
            float m = l1 + l2 + l3 + l4;
            yB.x = l0 + m;  yB.y = m + l5;
        }
        {
            const float* p = &rsST[rbuf][y0][tx];
            float l0=p[0], l1=p[RSP], l2=p[2*RSP], l3=p[3*RSP], l4=p[4*RSP], l5=p[5*RSP];
            float m = l1 + l2 + l3 + l4;
            yC.x = l0 + m;  yC.y = m + l5;
        }
        zS.x += yS.x - q0s.x;  zS.y += yS.y - q0s.y;
        zT.x += yT.x - q0t.x;  zT.y += yT.y - q0t.y;
        zA.x += yA.x - q0a.x;  zA.y += yA.y - q0a.y;
        zB.x += yB.x - q0b.x;  zB.y += yB.y - q0b.y;
        zC.x += yC.x - q0c.x;  zC.y += yC.y - q0c.y;
        q0s=q1s; q0t=q1t; q0a=q1a; q0b=q1b; q0c=q1c;
        q1s=q2s; q1t=q2t; q1a=q2a; q1b=q2b; q1c=q2c;
        q2s=q3s; q2t=q3t; q2a=q3a; q2b=q3b; q2c=q3c;
        q3s=q4s; q3t=q4t; q3a=q4a; q3b=q4b; q3c=q4c;
        q4s=yS;  q4t=yT;  q4a=yA;  q4b=yB;  q4c=yC;
        if (j >= 4) {
            const float inv = 1.0f / 125.0f;
            {
                float ms = zS.x * inv, mt = zT.x * inv;
                float vs = fmaf(-ms, ms, zA.x * inv);
                float vt = fmaf(-mt, mt, zB.x * inv);
                float cr = fmaf(-ms, mt, zC.x * inv);
                float den = fmaf(vs, vt, 1e-5f);
                lsum = fmaf(cr * cr, __builtin_amdgcn_rcpf(den), lsum);
            }
            {
                float ms = zS.y * inv, mt = zT.y * inv;
                float vs = fmaf(-ms, ms, zA.y * inv);
                float vt = fmaf(-mt, mt, zB.y * inv);
                float cr = fmaf(-ms, mt, zC.y * inv);
                float den = fmaf(vs, vt, 1e-5f);
                lsum = fmaf(cr * cr, __builtin_amdgcn_rcpf(den), lsum);
            }
        }
    };

    // phase1: sliding x-window, 6 raw words -> 2 rowsums per array
    auto rowsum = [&](int buf, int row) {
        const float* pS = &rawS[buf][row][rc];
        const float* pT = &rawT[buf][row][rc];
        float v0=pS[0],v1=pS[1],v2=pS[2],v3=pS[3],v4=pS[4],v5=pS[5];
        float u0=pT[0],u1=pT[1],u2=pT[2],u3=pT[3],u4=pT[4],u5=pT[5];
        float m  = v1 + v2 + v3 + v4;
        float n  = u1 + u2 + u3 + u4;
        float qS = fmaf(v1,v1, fmaf(v2,v2, fmaf(v3,v3, v4*v4)));
        float qT = fmaf(u1,u1, fmaf(u2,u2, fmaf(u3,u3, u4*u4)));
        float qX = fmaf(v1,u1, fmaf(v2,u2, fmaf(v3,u3, v4*u4)));
        rsS [buf][row][wc]   = v0 + m;
        rsS [buf][row][wc+1] = m + v5;
        rsT [buf][row][wc]   = u0 + n;
        rsT [buf][row][wc+1] = n + u5;
        rsS2[buf][row][wc]   = fmaf(v0,v0,qS);
        rsS2[buf][row][wc+1] = fmaf(v5,v5,qS);
        rsT2[buf][row][wc]   = fmaf(u0,u0,qT);
        rsT2[buf][row][wc+1] = fmaf(u5,u5,qT);
        rsST[buf][row][wc]   = fmaf(v0,u0,qX);
        rsST[buf][row][wc+1] = fmaf(v5,u5,qX);
    };

    // ---- prologue: stage plane zp = z0-2 into raw[0] ----
    {
        float4 vS = make_float4(0,0,0,0), vT = make_float4(0,0,0,0);
        const int zp = z0 - 2;
        if (zp >= 0 && sOk) {
            const size_t base = (size_t)(b * D_ + zp) * (size_t)HW_;
            vS = *(const float4*)(src + base + sOff);
            vT = *(const float4*)(tgt + base + sOff);
        }
        if (sW) {
            rawS[0][sr][sc]=vS.x; rawS[0][sr][sc+1]=vS.y; rawS[0][sr][sc+2]=vS.z; rawS[0][sr][sc+3]=vS.w;
            rawT[0][sr][sc]=vT.x; rawT[0][sr][sc+1]=vT.y; rawT[0][sr][sc+2]=vT.z; rawT[0][sr][sc+3]=vT.w;
        }
    }

    for (int i = 0; i < PLANES; ++i) {
        const int buf = i & 1;
        __syncthreads();   // the ONLY barrier per plane
        // -- issue global loads for plane i+1 (consumed at loop end) --
        float4 vS = make_float4(0,0,0,0), vT = make_float4(0,0,0,0);
        const bool haveNext = (i + 1 < PLANES);
        const int  zpn = z0 - 1 + i;
        if (haveNext && zpn >= 0 && zpn < D_ && sOk) {
            const size_t base = (size_t)(b * D_ + zpn) * (size_t)HW_;
            vS = *(const float4*)(src + base + sOff);
            vT = *(const float4*)(tgt + base + sOff);
        }
        // -- phase2 for plane i-1 (rowsums written last iteration) --
        if (i >= 1) phase2(buf ^ 1, i - 1);
        // -- phase1 for plane i: x-rowsums raw[buf] -> rs[buf] --
        rowsum(buf, p0y);
        if (p1) rowsum(buf, p1y);
        // -- write staged plane i+1 into raw[buf^1] (vmcnt wait lands here) --
        if (haveNext && sW) {
            rawS[buf^1][sr][sc]=vS.x; rawS[buf^1][sr][sc+1]=vS.y; rawS[buf^1][sr][sc+2]=vS.z; rawS[buf^1][sr][sc+3]=vS.w;
            rawT[buf^1][sr][sc]=vT.x; rawT[buf^1][sr][sc+1]=vT.y; rawT[buf^1][sr][sc+2]=vT.z; rawT[buf^1][sr][sc+3]=vT.w;
        }
    }
    __syncthreads();
    phase2((PLANES - 1) & 1, PLANES - 1);   // drain the pipeline

    // block reduction -> per-block partial (no atomics, no zero-kernel)
    #pragma unroll
    for (int off = 32; off > 0; off >>= 1)
        lsum += __shfl_down(lsum, off, 64);
    if ((tid & 63) == 0) wsum[tid >> 6] = lsum;
    __syncthreads();
    if (tid == 0) {
        const int bid = (blockIdx.z * GY + blockIdx.y) * GX + blockIdx.x;
        partial[bid] = wsum[0] + wsum[1] + wsum[2] + wsum[3];
    }
}

__global__ __launch_bounds__(256) void lncc_finalize(const float* __restrict__ partial,
                                                     float* __restrict__ out) {
    __shared__ float ws[4];
    const int t = threadIdx.x;
    float s = 0.0f;
    for (int i = t; i < NBLK; i += 256) s += partial[i];
    #pragma unroll
    for (int off = 32; off > 0; off >>= 1) s += __shfl_down(s, off, 64);
    if ((t & 63) == 0) ws[t >> 6] = s;
    __syncthreads();
    if (t == 0) {
        float tot = ws[0] + ws[1] + ws[2] + ws[3];
        float loss = 1.0f - tot * (1.0f / NTOT);
        if (isnan(loss) || isinf(loss)) loss = 1.0f;
        *out = loss;
    }
}

extern "C" void kernel_launch(void* const* d_in, const int* in_sizes, int n_in,
                              void* d_out, int out_size, void* d_ws, size_t ws_size,
                              hipStream_t stream) {
    const float* src = (const float*)d_in[0];
    const float* tgt = (const float*)d_in[1];
    float* out = (float*)d_out;
    float* partial = (float*)d_ws;   // NBLK floats of scratch

    dim3 grid(GX, GY, GZ);           // 6 x 12 x 16 = 1152 blocks
    dim3 block(256, 1, 1);
    lncc_main<<<grid, block, 0, stream>>>(src, tgt, partial);
    lncc_finalize<<<dim3(1), dim3(256), 0, stream>>>(partial, out);
}

// Round 4
// 153.131 us; speedup vs baseline: 1.1135x; 1.0403x over previous
//
#include <hip/hip_runtime.h>
#include <math.h>

// Problem constants (fixed by setup_inputs)
#define W_ 192
#define H_ 192
#define D_ 160
#define B_ 2
#define HW_ (H_ * W_)

#define TX 32             // output tile x
#define TY 8              // output tile y
#define HY 12             // halo rows (TY + 4)
#define RAWP 41           // raw row stride, 40 data cols + odd stride (<=2-way banks)
#define RSP  33           // rowsum row stride, 32 data cols + odd stride (<=2-way banks)
#define CHUNK 20          // z-planes of output per block
#define PLANES (CHUNK + 4)
#define GX 6              // 192/32
#define GY 24             // 192/8
#define GZ 16             // 8 z-chunks * 2 batches
#define NBLK (GX * GY * GZ)   // 2304
#define NTOT 11796480.0f      // 2*1*160*192*192

__global__ __launch_bounds__(256) void lncc_main(const float* __restrict__ src,
                                                 const float* __restrict__ tgt,
                                                 float* __restrict__ partial) {
    // SoA float LDS, double-buffered for the 1-barrier/plane pipeline.
    // Total 23728 B -> 6 blocks/CU resident (vs 4 at TY=16).
    __shared__ float rawS[2][HY][RAWP];
    __shared__ float rawT[2][HY][RAWP];
    __shared__ float rsS [2][HY][RSP];
    __shared__ float rsT [2][HY][RSP];
    __shared__ float rsS2[2][HY][RSP];
    __shared__ float rsT2[2][HY][RSP];
    __shared__ float rsST[2][HY][RSP];
    __shared__ float wsum[4];

    const int tid = threadIdx.x;
    const int bz  = blockIdx.z;
    const int b   = bz >> 3;                 // 8 chunks per batch
    const int z0  = (bz & 7) * CHUNK;
    const int bx0 = blockIdx.x * TX - 4;     // raw col 0 <-> gx = bx0 (16B-aligned)
    const int by0 = blockIdx.y * TY - 2;

    // ---- staging decode: tid<120 loads one aligned float4 per array ----
    const int  sr  = tid / 10;               // row 0..11
    const int  sc4 = tid - sr * 10;          // float4 col 0..9
    const int  sc  = sc4 * 4;                // word col 0,4,..,36
    const int  sgx = bx0 + sc;               // multiple of 4 -> float4 aligned
    const int  sgy = by0 + sr;
    const bool sW  = (tid < 120);
    const bool sOk = sW && ((unsigned)sgx < (unsigned)W_) && ((unsigned)sgy < (unsigned)H_);
    const size_t sOff = (size_t)sgy * W_ + (size_t)sgx;   // valid only when sOk

    // ---- phase1 decode: 16 x-pairs x 12 rows = 192 threads, one rep ----
    const int  p0y = tid >> 4;               // row 0..15 (only <12 active)
    const int  xp  = tid & 15;
    const bool pAct = (tid < 192);
    const int  rc  = 2 * xp + 2;             // raw read col base (window of out 2*xp)
    const int  wc  = 2 * xp;                 // rs write col base

    // ---- phase2 decode: thread owns output row y0, column tx ----
    const int tx = tid & 31;                 // 0..31
    const int y0 = tid >> 5;                 // 0..7

    // z-ring: 5 slots x 5 quantities, named scalars (arrays -> scratch).
    float q0s=0,q0t=0,q0a=0,q0b=0,q0c=0;
    float q1s=0,q1t=0,q1a=0,q1b=0,q1c=0;
    float q2s=0,q2t=0,q2a=0,q2b=0,q2c=0;
    float q3s=0,q3t=0,q3a=0,q3b=0,q3c=0;
    float q4s=0,q4t=0,q4a=0,q4b=0,q4c=0;
    float zS=0,zT=0,zA=0,zB=0,zC=0;
    float lsum = 0.0f;

    // phase2: y-sum of rowsums for plane j (buffer rbuf) + z-window + LNCC
    auto phase2 = [&](int rbuf, int j) {
        float yS,yT,yA,yB,yC;
        {
            const float* p = &rsS[rbuf][y0][tx];
            yS = p[0] + p[RSP] + p[2*RSP] + p[3*RSP] + p[4*RSP];
        }
        {
            const float* p = &rsT[rbuf][y0][tx];
            yT = p[0] + p[RSP] + p[2*RSP] + p[3*RSP] + p[4*RSP];
        }
        {
            const float* p = &rsS2[rbuf][y0][tx];
            yA = p[0] + p[RSP] + p[2*RSP] + p[3*RSP] + p[4*RSP];
        }
        {
            const float* p = &rsT2[rbuf][y0][tx];
            yB = p[0] + p[RSP] + p[2*RSP] + p[3*RSP] + p[4*RSP];
        }
        {
            const float* p = &rsST[rbuf][y0][tx];
            yC = p[0] + p[RSP] + p[2*RSP] + p[3*RSP] + p[4*RSP];
        }
        zS += yS - q0s;  zT += yT - q0t;  zA += yA - q0a;
        zB += yB - q0b;  zC += yC - q0c;
        q0s=q1s; q0t=q1t; q0a=q1a; q0b=q1b; q0c=q1c;
        q1s=q2s; q1t=q2t; q1a=q2a; q1b=q2b; q1c=q2c;
        q2s=q3s; q2t=q3t; q2a=q3a; q2b=q3b; q2c=q3c;
        q3s=q4s; q3t=q4t; q3a=q4a; q3b=q4b; q3c=q4c;
        q4s=yS;  q4t=yT;  q4a=yA;  q4b=yB;  q4c=yC;
        if (j >= 4) {
            const float inv = 1.0f / 125.0f;
            float ms = zS * inv, mt = zT * inv;
            float vs = fmaf(-ms, ms, zA * inv);
            float vt = fmaf(-mt, mt, zB * inv);
            float cr = fmaf(-ms, mt, zC * inv);
            float den = fmaf(vs, vt, 1e-5f);
            lsum = fmaf(cr * cr, __builtin_amdgcn_rcpf(den), lsum);
        }
    };

    // phase1: sliding x-window, 6 raw words -> 2 rowsums per array
    auto rowsum = [&](int buf, int row) {
        const float* pS = &rawS[buf][row][rc];
        const float* pT = &rawT[buf][row][rc];
        float v0=pS[0],v1=pS[1],v2=pS[2],v3=pS[3],v4=pS[4],v5=pS[5];
        float u0=pT[0],u1=pT[1],u2=pT[2],u3=pT[3],u4=pT[4],u5=pT[5];
        float m  = v1 + v2 + v3 + v4;
        float n  = u1 + u2 + u3 + u4;
        float qS = fmaf(v1,v1, fmaf(v2,v2, fmaf(v3,v3, v4*v4)));
        float qT = fmaf(u1,u1, fmaf(u2,u2, fmaf(u3,u3, u4*u4)));
        float qX = fmaf(v1,u1, fmaf(v2,u2, fmaf(v3,u3, v4*u4)));
        rsS [buf][row][wc]   = v0 + m;
        rsS [buf][row][wc+1] = m + v5;
        rsT [buf][row][wc]   = u0 + n;
        rsT [buf][row][wc+1] = n + u5;
        rsS2[buf][row][wc]   = fmaf(v0,v0,qS);
        rsS2[buf][row][wc+1] = fmaf(v5,v5,qS);
        rsT2[buf][row][wc]   = fmaf(u0,u0,qT);
        rsT2[buf][row][wc+1] = fmaf(u5,u5,qT);
        rsST[buf][row][wc]   = fmaf(v0,u0,qX);
        rsST[buf][row][wc+1] = fmaf(v5,u5,qX);
    };

    // ---- prologue: stage plane zp = z0-2 into raw[0] ----
    {
        float4 vS = make_float4(0,0,0,0), vT = make_float4(0,0,0,0);
        const int zp = z0 - 2;
        if (zp >= 0 && sOk) {
            const size_t base = (size_t)(b * D_ + zp) * (size_t)HW_;
            vS = *(const float4*)(src + base + sOff);
            vT = *(const float4*)(tgt + base + sOff);
        }
        if (sW) {
            rawS[0][sr][sc]=vS.x; rawS[0][sr][sc+1]=vS.y; rawS[0][sr][sc+2]=vS.z; rawS[0][sr][sc+3]=vS.w;
            rawT[0][sr][sc]=vT.x; rawT[0][sr][sc+1]=vT.y; rawT[0][sr][sc+2]=vT.z; rawT[0][sr][sc+3]=vT.w;
        }
    }

    for (int i = 0; i < PLANES; ++i) {
        const int buf = i & 1;
        __syncthreads();   // the ONLY barrier per plane
        // -- issue global loads for plane i+1 (consumed at loop end) --
        float4 vS = make_float4(0,0,0,0), vT = make_float4(0,0,0,0);
        const bool haveNext = (i + 1 < PLANES);
        const int  zpn = z0 - 1 + i;
        if (haveNext && zpn >= 0 && zpn < D_ && sOk) {
            const size_t base = (size_t)(b * D_ + zpn) * (size_t)HW_;
            vS = *(const float4*)(src + base + sOff);
            vT = *(const float4*)(tgt + base + sOff);
        }
        // -- phase2 for plane i-1 (rowsums written last iteration) --
        if (i >= 1) phase2(buf ^ 1, i - 1);
        // -- phase1 for plane i: x-rowsums raw[buf] -> rs[buf] --
        if (pAct && p0y < HY) rowsum(buf, p0y);
        // -- write staged plane i+1 into raw[buf^1] (vmcnt wait lands here) --
        if (haveNext && sW) {
            rawS[buf^1][sr][sc]=vS.x; rawS[buf^1][sr][sc+1]=vS.y; rawS[buf^1][sr][sc+2]=vS.z; rawS[buf^1][sr][sc+3]=vS.w;
            rawT[buf^1][sr][sc]=vT.x; rawT[buf^1][sr][sc+1]=vT.y; rawT[buf^1][sr][sc+2]=vT.z; rawT[buf^1][sr][sc+3]=vT.w;
        }
    }
    __syncthreads();
    phase2((PLANES - 1) & 1, PLANES - 1);   // drain the pipeline

    // block reduction -> per-block partial (no atomics, no zero-kernel)
    #pragma unroll
    for (int off = 32; off > 0; off >>= 1)
        lsum += __shfl_down(lsum, off, 64);
    if ((tid & 63) == 0) wsum[tid >> 6] = lsum;
    __syncthreads();
    if (tid == 0) {
        const int bid = (blockIdx.z * GY + blockIdx.y) * GX + blockIdx.x;
        partial[bid] = wsum[0] + wsum[1] + wsum[2] + wsum[3];
    }
}

__global__ __launch_bounds__(256) void lncc_finalize(const float* __restrict__ partial,
                                                     float* __restrict__ out) {
    __shared__ float ws[4];
    const int t = threadIdx.x;
    float s = 0.0f;
    for (int i = t; i < NBLK; i += 256) s += partial[i];
    #pragma unroll
    for (int off = 32; off > 0; off >>= 1) s += __shfl_down(s, off, 64);
    if ((t & 63) == 0) ws[t >> 6] = s;
    __syncthreads();
    if (t == 0) {
        float tot = ws[0] + ws[1] + ws[2] + ws[3];
        float loss = 1.0f - tot * (1.0f / NTOT);
        if (isnan(loss) || isinf(loss)) loss = 1.0f;
        *out = loss;
    }
}

extern "C" void kernel_launch(void* const* d_in, const int* in_sizes, int n_in,
                              void* d_out, int out_size, void* d_ws, size_t ws_size,
                              hipStream_t stream) {
    const float* src = (const float*)d_in[0];
    const float* tgt = (const float*)d_in[1];
    float* out = (float*)d_out;
    float* partial = (float*)d_ws;   // NBLK floats of scratch

    dim3 grid(GX, GY, GZ);           // 6 x 24 x 16 = 2304 blocks
    dim3 block(256, 1, 1);
    lncc_main<<<grid, block, 0, stream>>>(src, tgt, partial);
    lncc_finalize<<<dim3(1), dim3(256), 0, stream>>>(partial, out);
}